// Round 2
// baseline (243.488 us; speedup 1.0000x reference)
//
#include <hip/hip_runtime.h>

#define S_LEN 256
#define H_DIM 768
#define T_HEADS 13
#define WN 1664
#define NEGV 1.0e12f

typedef __bf16 bf16x8 __attribute__((ext_vector_type(8)));
typedef float f32x4 __attribute__((ext_vector_type(4)));

static __device__ __forceinline__ ushort f2bf(float x) {
  unsigned u = __float_as_uint(x);
  return (ushort)((u + 0x7FFFu + ((u >> 16) & 1u)) >> 16);
}

__global__ __launch_bounds__(256, 2) void gp_kernel(
    const float* __restrict__ lhs, const float* __restrict__ Wd,
    const float* __restrict__ bias, const float* __restrict__ amask,
    float* __restrict__ out) {
  // XCD-aware bijective swizzle: 832 blocks = 8 XCDs x 104; each XCD gets 8
  // consecutive batches -> lhs[b] (768 KB) stays L2-resident for its 13 heads.
  const int bid0 = blockIdx.x;
  const int bid = (bid0 & 7) * 104 + (bid0 >> 3);
  const int b = bid / T_HEADS;
  const int th = bid % T_HEADS;
  const int wcol0 = th * 128;
  const int tid = threadIdx.x;
  const int w = tid >> 6;
  const int lane = tid & 63;
  const int lo = lane & 15;
  const int hi = lane >> 4;

  // LDS overlay: phase-1 staging (A,W) and phase-2 (Q,K) never live together.
  // p1: 256*72*2 + 128*72*2 = 54 KB ; p2: 2*256*72*2 = 72 KB ; union+mask = 73 KB
  // -> 2 blocks/CU (was 103 KB -> 1 block/CU).
  __shared__ union {
    struct { ushort A[256][72]; ushort W[128][72]; } p1;
    struct { ushort Q[256][72]; ushort K[256][72]; } p2;
  } sm;
  __shared__ float mask_s[256];

  mask_s[tid] = amask[b * S_LEN + tid];

  f32x4 acc[4][8];
#pragma unroll
  for (int mi = 0; mi < 4; ++mi)
#pragma unroll
    for (int ni = 0; ni < 8; ++ni) acc[mi][ni] = (f32x4){0.f, 0.f, 0.f, 0.f};

  const float* Ab = lhs + (size_t)b * (S_LEN * H_DIM);
  const int wc4 = tid & 31;   // W stage: col-group of 4
  const int wrg = tid >> 5;   // W stage: row-group of 8

  // ---------------- phase 1: P = lhs[b] @ W[:, t*128 : t*128+128], BK=64 ----------------
  for (int k0 = 0; k0 < H_DIM; k0 += 64) {
    // stage A chunk 256x64 f32->bf16 (16 float4/thread, coalesced)
#pragma unroll
    for (int p = 0; p < 16; ++p) {
      int f = p * 256 + tid;
      int m = f >> 4;
      int c4 = f & 15;
      float4 v = *reinterpret_cast<const float4*>(Ab + (size_t)m * H_DIM + k0 + c4 * 4);
      *reinterpret_cast<ushort4*>(&sm.p1.A[m][c4 * 4]) =
          make_ushort4(f2bf(v.x), f2bf(v.y), f2bf(v.z), f2bf(v.w));
    }
    // stage W chunk transposed: 8 float4 loads (coalesced 512B/32lanes) + reg transpose
    {
      ushort wt[8][4];
#pragma unroll
      for (int r8 = 0; r8 < 8; ++r8) {
        float4 v = *reinterpret_cast<const float4*>(
            Wd + (size_t)(k0 + wrg * 8 + r8) * WN + wcol0 + wc4 * 4);
        wt[r8][0] = f2bf(v.x); wt[r8][1] = f2bf(v.y);
        wt[r8][2] = f2bf(v.z); wt[r8][3] = f2bf(v.w);
      }
#pragma unroll
      for (int cc = 0; cc < 4; ++cc) {
        *reinterpret_cast<ushort4*>(&sm.p1.W[wc4 * 4 + cc][wrg * 8]) =
            make_ushort4(wt[0][cc], wt[1][cc], wt[2][cc], wt[3][cc]);
        *reinterpret_cast<ushort4*>(&sm.p1.W[wc4 * 4 + cc][wrg * 8 + 4]) =
            make_ushort4(wt[4][cc], wt[5][cc], wt[6][cc], wt[7][cc]);
      }
    }
    __syncthreads();

#pragma unroll
    for (int kk = 0; kk < 2; ++kk) {
      bf16x8 af[4];
#pragma unroll
      for (int mi = 0; mi < 4; ++mi)
        af[mi] = *reinterpret_cast<const bf16x8*>(&sm.p1.A[w * 64 + mi * 16 + lo][kk * 32 + hi * 8]);
#pragma unroll
      for (int ni = 0; ni < 8; ++ni) {
        bf16x8 bfr = *reinterpret_cast<const bf16x8*>(&sm.p1.W[ni * 16 + lo][kk * 32 + hi * 8]);
#pragma unroll
        for (int mi = 0; mi < 4; ++mi)
          acc[mi][ni] = __builtin_amdgcn_mfma_f32_16x16x32_bf16(af[mi], bfr, acc[mi][ni], 0, 0, 0);
      }
    }
    __syncthreads();
  }

  // ---------------- bias + RoPE + write Q/K to LDS (overlaid) ----------------
  float bj[8];
#pragma unroll
  for (int ni = 0; ni < 8; ++ni) bj[ni] = bias[wcol0 + ni * 16 + lo];

  float inv_[4];
#pragma unroll
  for (int ii = 0; ii < 4; ++ii)
    inv_[ii] = exp2f(-(float)(ii * 8 + (lo >> 1)) * 0.4152410118609203f);  // log2(1e4)/32
  const float sgn = (lo & 1) ? 1.0f : -1.0f;

#pragma unroll
  for (int mi = 0; mi < 4; ++mi) {
#pragma unroll
    for (int r = 0; r < 4; ++r) {
      int m = w * 64 + mi * 16 + hi * 4 + r;  // C/D row mapping (verified R1)
#pragma unroll
      for (int ii = 0; ii < 4; ++ii) {
        float sv, cv;
        __sincosf((float)m * inv_[ii], &sv, &cv);
        {  // q half: cols 0..63
          float v = acc[mi][ii][r] + bj[ii];
          float o = __shfl_xor(v, 1);
          sm.p2.Q[m][ii * 16 + lo] = f2bf(v * cv + sgn * o * sv);
        }
        {  // k half: cols 64..127
          float v = acc[mi][ii + 4][r] + bj[ii + 4];
          float o = __shfl_xor(v, 1);
          sm.p2.K[m][ii * 16 + lo] = f2bf(v * cv + sgn * o * sv);
        }
      }
    }
  }
  __syncthreads();

  // ---------------- phase 2: logits = Q @ K^T, mask, scale, store ----------------
  bf16x8 qf[4][2];
#pragma unroll
  for (int mi = 0; mi < 4; ++mi)
#pragma unroll
    for (int ks = 0; ks < 2; ++ks)
      qf[mi][ks] = *reinterpret_cast<const bf16x8*>(&sm.p2.Q[w * 64 + mi * 16 + lo][ks * 32 + hi * 8]);

  const size_t outbase = (size_t)bid * (S_LEN * (size_t)S_LEN);
#pragma unroll 1
  for (int nc = 0; nc < 4; ++nc) {
    bf16x8 kf[4][2];
#pragma unroll
    for (int ni = 0; ni < 4; ++ni)
#pragma unroll
      for (int ks = 0; ks < 2; ++ks)
        kf[ni][ks] = *reinterpret_cast<const bf16x8*>(&sm.p2.K[nc * 64 + ni * 16 + lo][ks * 32 + hi * 8]);

    f32x4 a2[4][4];
#pragma unroll
    for (int mi = 0; mi < 4; ++mi)
#pragma unroll
      for (int ni = 0; ni < 4; ++ni) a2[mi][ni] = (f32x4){0.f, 0.f, 0.f, 0.f};
#pragma unroll
    for (int ks = 0; ks < 2; ++ks)
#pragma unroll
      for (int mi = 0; mi < 4; ++mi)
#pragma unroll
        for (int ni = 0; ni < 4; ++ni)
          a2[mi][ni] = __builtin_amdgcn_mfma_f32_16x16x32_bf16(qf[mi][ks], kf[ni][ks], a2[mi][ni], 0, 0, 0);

#pragma unroll
    for (int mi = 0; mi < 4; ++mi) {
#pragma unroll
      for (int ni = 0; ni < 4; ++ni) {
        int n = nc * 64 + ni * 16 + lo;
        float pad = mask_s[n];
        float sub = (1.0f - pad) * NEGV;
#pragma unroll
        for (int r = 0; r < 4; ++r) {
          int m = w * 64 + mi * 16 + hi * 4 + r;
          float v = a2[mi][ni][r];
          v = v * pad - sub;
          if (m > n) v -= NEGV;  // tril(.., -1)
          __builtin_nontemporal_store(v * 0.125f, &out[outbase + (size_t)m * S_LEN + n]);
        }
      }
    }
  }
}

extern "C" void kernel_launch(void* const* d_in, const int* in_sizes, int n_in,
                              void* d_out, int out_size, void* d_ws, size_t ws_size,
                              hipStream_t stream) {
  const float* lhs = (const float*)d_in[0];    // (64,256,768) f32
  const float* Wd = (const float*)d_in[1];     // (768,1664) f32
  const float* bias = (const float*)d_in[2];   // (1664,) f32
  const float* amask = (const float*)d_in[3];  // (64,256) f32
  float* out = (float*)d_out;                  // (64,13,256,256) f32

  dim3 grid(64 * T_HEADS);  // 832 blocks, one per (b, head)
  gp_kernel<<<grid, 256, 0, stream>>>(lhs, Wd, bias, amask, out);
}

// Round 3
// 225.907 us; speedup vs baseline: 1.0778x; 1.0778x over previous
//
#include <hip/hip_runtime.h>

#define S_LEN 256
#define H_DIM 768
#define T_HEADS 13
#define WN 1664
#define NEGV 1.0e12f

typedef __bf16 bf16x8 __attribute__((ext_vector_type(8)));
typedef float f32x4 __attribute__((ext_vector_type(4)));

static __device__ __forceinline__ ushort f2bf(float x) {
  unsigned u = __float_as_uint(x);
  return (ushort)((u + 0x7FFFu + ((u >> 16) & 1u)) >> 16);
}

// ---- prep 1: lhs f32 -> bf16, same [64][256][768] layout ----
__global__ __launch_bounds__(256) void prep_lhs(const float* __restrict__ in,
                                                ushort* __restrict__ outb) {
  size_t base = ((size_t)blockIdx.x * 256 + threadIdx.x) * 8;
  float4 v0 = *reinterpret_cast<const float4*>(in + base);
  float4 v1 = *reinterpret_cast<const float4*>(in + base + 4);
  uint4 u;
  u.x = f2bf(v0.x) | ((unsigned)f2bf(v0.y) << 16);
  u.y = f2bf(v0.z) | ((unsigned)f2bf(v0.w) << 16);
  u.z = f2bf(v1.x) | ((unsigned)f2bf(v1.y) << 16);
  u.w = f2bf(v1.z) | ((unsigned)f2bf(v1.w) << 16);
  *reinterpret_cast<uint4*>(outb + base) = u;
}

// ---- prep 2: W [768][1664] f32 -> Wt [1664][768] bf16 (transpose) ----
__global__ __launch_bounds__(256) void prep_wt(const float* __restrict__ W,
                                               ushort* __restrict__ Wt) {
  __shared__ ushort T[64][68];
  const int blk = blockIdx.x;
  const int k0 = (blk % 12) * 64, c0 = (blk / 12) * 64;
  const int tid = threadIdx.x;
#pragma unroll
  for (int p = 0; p < 4; ++p) {
    int f = p * 256 + tid;
    int r = f >> 4, cg = f & 15;
    float4 v = *reinterpret_cast<const float4*>(W + (size_t)(k0 + r) * WN + c0 + cg * 4);
    T[r][cg * 4 + 0] = f2bf(v.x); T[r][cg * 4 + 1] = f2bf(v.y);
    T[r][cg * 4 + 2] = f2bf(v.z); T[r][cg * 4 + 3] = f2bf(v.w);
  }
  __syncthreads();
  const int orow = tid >> 2, kq = tid & 3;
  ushort tmp[16];
#pragma unroll
  for (int j = 0; j < 16; ++j) tmp[j] = T[kq * 16 + j][orow];
  uint4 u0, u1;
  u0.x = tmp[0] | ((unsigned)tmp[1] << 16);  u0.y = tmp[2] | ((unsigned)tmp[3] << 16);
  u0.z = tmp[4] | ((unsigned)tmp[5] << 16);  u0.w = tmp[6] | ((unsigned)tmp[7] << 16);
  u1.x = tmp[8] | ((unsigned)tmp[9] << 16);  u1.y = tmp[10] | ((unsigned)tmp[11] << 16);
  u1.z = tmp[12] | ((unsigned)tmp[13] << 16); u1.w = tmp[14] | ((unsigned)tmp[15] << 16);
  ushort* dst = Wt + (size_t)(c0 + orow) * H_DIM + k0 + kq * 16;
  *reinterpret_cast<uint4*>(dst) = u0;
  *reinterpret_cast<uint4*>(dst + 8) = u1;
}

// ---- fused main kernel ----
template <bool PREP>
__global__ __launch_bounds__(256, 2) void gp_kernel(
    const float* __restrict__ lhs, const float* __restrict__ Wd,
    const float* __restrict__ bias, const float* __restrict__ amask,
    const ushort* __restrict__ lhsb, const ushort* __restrict__ Wt,
    float* __restrict__ out) {
  const int bid0 = blockIdx.x;
  const int bid = (bid0 & 7) * 104 + (bid0 >> 3);  // XCD swizzle (832 = 8*104)
  const int b = bid / T_HEADS;
  const int th = bid % T_HEADS;
  const int wcol0 = th * 128;
  const int tid = threadIdx.x;
  const int w = tid >> 6;
  const int lane = tid & 63;
  const int lo = lane & 15;
  const int hi = lane >> 4;

  __shared__ union {
    struct { ushort A[256][72]; ushort W[128][72]; } p1;
    struct { ushort Q[256][72]; ushort K[256][72]; } p2;
  } sm;
  __shared__ float mask_s[256];

  mask_s[tid] = amask[b * S_LEN + tid];

  f32x4 acc[4][8];
#pragma unroll
  for (int mi = 0; mi < 4; ++mi)
#pragma unroll
    for (int ni = 0; ni < 8; ++ni) acc[mi][ni] = (f32x4){0.f, 0.f, 0.f, 0.f};

  // ---------------- phase 1: P = lhs[b] @ W[:, t*128 : +128], BK=64 ----------------
  if constexpr (PREP) {
    const ushort* Ab = lhsb + (size_t)b * (S_LEN * H_DIM);
    const ushort* Wb = Wt + (size_t)wcol0 * H_DIM;
    uint4 pa[8], pw[4];
    // prologue: prefetch tile 0
#pragma unroll
    for (int p = 0; p < 8; ++p) {
      int f = p * 256 + tid;
      pa[p] = *reinterpret_cast<const uint4*>(Ab + (size_t)(f >> 3) * H_DIM + (f & 7) * 8);
    }
#pragma unroll
    for (int p = 0; p < 4; ++p) {
      int f = p * 256 + tid;
      pw[p] = *reinterpret_cast<const uint4*>(Wb + (size_t)(f >> 3) * H_DIM + (f & 7) * 8);
    }
    for (int k0 = 0; k0 < H_DIM; k0 += 64) {
      // commit prefetched tile to LDS (slot rotation via 72-pad => conflict-free)
#pragma unroll
      for (int p = 0; p < 8; ++p) {
        int f = p * 256 + tid;
        *reinterpret_cast<uint4*>(&sm.p1.A[f >> 3][(f & 7) * 8]) = pa[p];
      }
#pragma unroll
      for (int p = 0; p < 4; ++p) {
        int f = p * 256 + tid;
        *reinterpret_cast<uint4*>(&sm.p1.W[f >> 3][(f & 7) * 8]) = pw[p];
      }
      __syncthreads();
      // prefetch next tile while MFMAing this one
      if (k0 + 64 < H_DIM) {
#pragma unroll
        for (int p = 0; p < 8; ++p) {
          int f = p * 256 + tid;
          pa[p] = *reinterpret_cast<const uint4*>(Ab + (size_t)(f >> 3) * H_DIM + k0 + 64 + (f & 7) * 8);
        }
#pragma unroll
        for (int p = 0; p < 4; ++p) {
          int f = p * 256 + tid;
          pw[p] = *reinterpret_cast<const uint4*>(Wb + (size_t)(f >> 3) * H_DIM + k0 + 64 + (f & 7) * 8);
        }
      }
#pragma unroll
      for (int kk = 0; kk < 2; ++kk) {
        bf16x8 af[4];
#pragma unroll
        for (int mi = 0; mi < 4; ++mi)
          af[mi] = *reinterpret_cast<const bf16x8*>(&sm.p1.A[w * 64 + mi * 16 + lo][kk * 32 + hi * 8]);
#pragma unroll
        for (int ni = 0; ni < 8; ++ni) {
          bf16x8 bfr = *reinterpret_cast<const bf16x8*>(&sm.p1.W[ni * 16 + lo][kk * 32 + hi * 8]);
#pragma unroll
          for (int mi = 0; mi < 4; ++mi)
            acc[mi][ni] = __builtin_amdgcn_mfma_f32_16x16x32_bf16(af[mi], bfr, acc[mi][ni], 0, 0, 0);
        }
      }
      __syncthreads();
    }
  } else {
    // fallback: stage f32 + convert in-kernel (R2-proven path)
    const float* Ab = lhs + (size_t)b * (S_LEN * H_DIM);
    const int wc4 = tid & 31, wrg = tid >> 5;
    for (int k0 = 0; k0 < H_DIM; k0 += 64) {
#pragma unroll
      for (int p = 0; p < 16; ++p) {
        int f = p * 256 + tid;
        int m = f >> 4, c4 = f & 15;
        float4 v = *reinterpret_cast<const float4*>(Ab + (size_t)m * H_DIM + k0 + c4 * 4);
        *reinterpret_cast<ushort4*>(&sm.p1.A[m][c4 * 4]) =
            make_ushort4(f2bf(v.x), f2bf(v.y), f2bf(v.z), f2bf(v.w));
      }
      {
        ushort wt[8][4];
#pragma unroll
        for (int r8 = 0; r8 < 8; ++r8) {
          float4 v = *reinterpret_cast<const float4*>(
              Wd + (size_t)(k0 + wrg * 8 + r8) * WN + wcol0 + wc4 * 4);
          wt[r8][0] = f2bf(v.x); wt[r8][1] = f2bf(v.y);
          wt[r8][2] = f2bf(v.z); wt[r8][3] = f2bf(v.w);
        }
#pragma unroll
        for (int cc = 0; cc < 4; ++cc) {
          *reinterpret_cast<ushort4*>(&sm.p1.W[wc4 * 4 + cc][wrg * 8]) =
              make_ushort4(wt[0][cc], wt[1][cc], wt[2][cc], wt[3][cc]);
          *reinterpret_cast<ushort4*>(&sm.p1.W[wc4 * 4 + cc][wrg * 8 + 4]) =
              make_ushort4(wt[4][cc], wt[5][cc], wt[6][cc], wt[7][cc]);
        }
      }
      __syncthreads();
#pragma unroll
      for (int kk = 0; kk < 2; ++kk) {
        bf16x8 af[4];
#pragma unroll
        for (int mi = 0; mi < 4; ++mi)
          af[mi] = *reinterpret_cast<const bf16x8*>(&sm.p1.A[w * 64 + mi * 16 + lo][kk * 32 + hi * 8]);
#pragma unroll
        for (int ni = 0; ni < 8; ++ni) {
          bf16x8 bfr = *reinterpret_cast<const bf16x8*>(&sm.p1.W[ni * 16 + lo][kk * 32 + hi * 8]);
#pragma unroll
          for (int mi = 0; mi < 4; ++mi)
            acc[mi][ni] = __builtin_amdgcn_mfma_f32_16x16x32_bf16(af[mi], bfr, acc[mi][ni], 0, 0, 0);
        }
      }
      __syncthreads();
    }
  }

  // ---------------- bias + RoPE + write Q/K to LDS (overlaid) ----------------
  float bj[8];
#pragma unroll
  for (int ni = 0; ni < 8; ++ni) bj[ni] = bias[wcol0 + ni * 16 + lo];

  float inv_[4];
#pragma unroll
  for (int ii = 0; ii < 4; ++ii)
    inv_[ii] = exp2f(-(float)(ii * 8 + (lo >> 1)) * 0.4152410118609203f);  // log2(1e4)/32
  const float sgn = (lo & 1) ? 1.0f : -1.0f;

#pragma unroll
  for (int mi = 0; mi < 4; ++mi) {
#pragma unroll
    for (int r = 0; r < 4; ++r) {
      int m = w * 64 + mi * 16 + hi * 4 + r;  // C/D row mapping (verified)
#pragma unroll
      for (int ii = 0; ii < 4; ++ii) {
        float sv, cv;
        __sincosf((float)m * inv_[ii], &sv, &cv);
        {
          float v = acc[mi][ii][r] + bj[ii];
          float o = __shfl_xor(v, 1);
          sm.p2.Q[m][ii * 16 + lo] = f2bf(v * cv + sgn * o * sv);
        }
        {
          float v = acc[mi][ii + 4][r] + bj[ii + 4];
          float o = __shfl_xor(v, 1);
          sm.p2.K[m][ii * 16 + lo] = f2bf(v * cv + sgn * o * sv);
        }
      }
    }
  }
  __syncthreads();

  // ---------------- phase 2: logits = Q @ K^T, mask, scale, store ----------------
  bf16x8 qf[4][2];
#pragma unroll
  for (int mi = 0; mi < 4; ++mi)
#pragma unroll
    for (int ks = 0; ks < 2; ++ks)
      qf[mi][ks] = *reinterpret_cast<const bf16x8*>(&sm.p2.Q[w * 64 + mi * 16 + lo][ks * 32 + hi * 8]);

  const size_t outbase = (size_t)bid * (S_LEN * (size_t)S_LEN);
#pragma unroll 1
  for (int nc = 0; nc < 4; ++nc) {
    bf16x8 kf[4][2];
#pragma unroll
    for (int ni = 0; ni < 4; ++ni)
#pragma unroll
      for (int ks = 0; ks < 2; ++ks)
        kf[ni][ks] = *reinterpret_cast<const bf16x8*>(&sm.p2.K[nc * 64 + ni * 16 + lo][ks * 32 + hi * 8]);

    f32x4 a2[4][4];
#pragma unroll
    for (int mi = 0; mi < 4; ++mi)
#pragma unroll
      for (int ni = 0; ni < 4; ++ni) a2[mi][ni] = (f32x4){0.f, 0.f, 0.f, 0.f};
#pragma unroll
    for (int ks = 0; ks < 2; ++ks)
#pragma unroll
      for (int mi = 0; mi < 4; ++mi)
#pragma unroll
        for (int ni = 0; ni < 4; ++ni)
          a2[mi][ni] = __builtin_amdgcn_mfma_f32_16x16x32_bf16(qf[mi][ks], kf[ni][ks], a2[mi][ni], 0, 0, 0);

#pragma unroll
    for (int mi = 0; mi < 4; ++mi) {
#pragma unroll
      for (int ni = 0; ni < 4; ++ni) {
        int n = nc * 64 + ni * 16 + lo;
        float pad = mask_s[n];
        float sub = (1.0f - pad) * NEGV;
#pragma unroll
        for (int r = 0; r < 4; ++r) {
          int m = w * 64 + mi * 16 + hi * 4 + r;
          float v = a2[mi][ni][r];
          v = v * pad - sub;
          if (m > n) v -= NEGV;  // tril(.., -1)
          out[outbase + (size_t)m * S_LEN + n] = v * 0.125f;
        }
      }
    }
  }
}

extern "C" void kernel_launch(void* const* d_in, const int* in_sizes, int n_in,
                              void* d_out, int out_size, void* d_ws, size_t ws_size,
                              hipStream_t stream) {
  const float* lhs = (const float*)d_in[0];    // (64,256,768) f32
  const float* Wd = (const float*)d_in[1];     // (768,1664) f32
  const float* bias = (const float*)d_in[2];   // (1664,) f32
  const float* amask = (const float*)d_in[3];  // (64,256) f32
  float* out = (float*)d_out;                  // (64,13,256,256) f32

  const size_t lhsb_elems = (size_t)64 * S_LEN * H_DIM;        // 12.58M ushort
  const size_t wt_elems = (size_t)WN * H_DIM;                  // 1.28M ushort
  const size_t need = (lhsb_elems + wt_elems) * sizeof(ushort);  // ~26.4 MB

  if (ws_size >= need) {
    ushort* lhsb = (ushort*)d_ws;
    ushort* wt = lhsb + lhsb_elems;
    prep_lhs<<<dim3((unsigned)(lhsb_elems / 8 / 256)), 256, 0, stream>>>(lhs, lhsb);
    prep_wt<<<dim3(12 * 26), 256, 0, stream>>>(Wd, wt);
    gp_kernel<true><<<dim3(64 * T_HEADS), 256, 0, stream>>>(lhs, Wd, bias, amask, lhsb, wt, out);
  } else {
    gp_kernel<false><<<dim3(64 * T_HEADS), 256, 0, stream>>>(lhs, Wd, bias, amask, nullptr, nullptr, out);
  }
}

// Round 4
// 215.543 us; speedup vs baseline: 1.1296x; 1.0481x over previous
//
#include <hip/hip_runtime.h>

#define S_LEN 256
#define H_DIM 768
#define T_HEADS 13
#define WN 1664
#define NEGV 1.0e12f

typedef __bf16 bf16x8 __attribute__((ext_vector_type(8)));
typedef float f32x4 __attribute__((ext_vector_type(4)));
typedef float f32x16 __attribute__((ext_vector_type(16)));

static __device__ __forceinline__ ushort f2bf(float x) {
  unsigned u = __float_as_uint(x);
  return (ushort)((u + 0x7FFFu + ((u >> 16) & 1u)) >> 16);
}

// ---- prep 1: lhs f32 -> bf16, same [64][256][768] layout ----
__global__ __launch_bounds__(256) void prep_lhs(const float* __restrict__ in,
                                                ushort* __restrict__ outb) {
  size_t base = ((size_t)blockIdx.x * 256 + threadIdx.x) * 8;
  float4 v0 = *reinterpret_cast<const float4*>(in + base);
  float4 v1 = *reinterpret_cast<const float4*>(in + base + 4);
  uint4 u;
  u.x = f2bf(v0.x) | ((unsigned)f2bf(v0.y) << 16);
  u.y = f2bf(v0.z) | ((unsigned)f2bf(v0.w) << 16);
  u.z = f2bf(v1.x) | ((unsigned)f2bf(v1.y) << 16);
  u.w = f2bf(v1.z) | ((unsigned)f2bf(v1.w) << 16);
  *reinterpret_cast<uint4*>(outb + base) = u;
}

// ---- prep 2: W [768][1664] f32 -> Wt [1664][768] bf16 (transpose) ----
__global__ __launch_bounds__(256) void prep_wt(const float* __restrict__ W,
                                               ushort* __restrict__ Wt) {
  __shared__ ushort T[64][68];
  const int blk = blockIdx.x;
  const int k0 = (blk % 12) * 64, c0 = (blk / 12) * 64;
  const int tid = threadIdx.x;
#pragma unroll
  for (int p = 0; p < 4; ++p) {
    int f = p * 256 + tid;
    int r = f >> 4, cg = f & 15;
    float4 v = *reinterpret_cast<const float4*>(W + (size_t)(k0 + r) * WN + c0 + cg * 4);
    T[r][cg * 4 + 0] = f2bf(v.x); T[r][cg * 4 + 1] = f2bf(v.y);
    T[r][cg * 4 + 2] = f2bf(v.z); T[r][cg * 4 + 3] = f2bf(v.w);
  }
  __syncthreads();
  const int orow = tid >> 2, kq = tid & 3;
  ushort tmp[16];
#pragma unroll
  for (int j = 0; j < 16; ++j) tmp[j] = T[kq * 16 + j][orow];
  uint4 u0, u1;
  u0.x = tmp[0] | ((unsigned)tmp[1] << 16);  u0.y = tmp[2] | ((unsigned)tmp[3] << 16);
  u0.z = tmp[4] | ((unsigned)tmp[5] << 16);  u0.w = tmp[6] | ((unsigned)tmp[7] << 16);
  u1.x = tmp[8] | ((unsigned)tmp[9] << 16);  u1.y = tmp[10] | ((unsigned)tmp[11] << 16);
  u1.z = tmp[12] | ((unsigned)tmp[13] << 16); u1.w = tmp[14] | ((unsigned)tmp[15] << 16);
  ushort* dst = Wt + (size_t)(c0 + orow) * H_DIM + k0 + kq * 16;
  *reinterpret_cast<uint4*>(dst) = u0;
  *reinterpret_cast<uint4*>(dst + 8) = u1;
}

// ---- fused main kernel ----
template <bool PREP>
__global__ __launch_bounds__(256, 2) void gp_kernel(
    const float* __restrict__ lhs, const float* __restrict__ Wd,
    const float* __restrict__ bias, const float* __restrict__ amask,
    const ushort* __restrict__ lhsb, const ushort* __restrict__ Wt,
    float* __restrict__ out) {
  const int bid0 = blockIdx.x;
  const int bid = (bid0 & 7) * 104 + (bid0 >> 3);  // XCD swizzle (832 = 8*104)
  const int b = bid / T_HEADS;
  const int th = bid % T_HEADS;
  const int wcol0 = th * 128;
  const int tid = threadIdx.x;
  const int w = tid >> 6;
  const int lane = tid & 63;
  const int lo = lane & 15;
  const int hi = lane >> 4;
  const int l31 = lane & 31;
  const int hi2 = lane >> 5;

  __shared__ union {
    struct { ushort A[256][72]; ushort W[128][72]; } p1;
    struct { ushort Q[256][72]; ushort K[256][72]; } p2;
  } sm;
  __shared__ float mask_s[256];

  mask_s[tid] = amask[b * S_LEN + tid];

  f32x4 acc[4][8];
#pragma unroll
  for (int mi = 0; mi < 4; ++mi)
#pragma unroll
    for (int ni = 0; ni < 8; ++ni) acc[mi][ni] = (f32x4){0.f, 0.f, 0.f, 0.f};

  // ---------------- phase 1: P = lhs[b] @ W[:, t*128 : +128], BK=64 ----------------
  if constexpr (PREP) {
    const ushort* Ab = lhsb + (size_t)b * (S_LEN * H_DIM);
    const ushort* Wb = Wt + (size_t)wcol0 * H_DIM;
    uint4 pa[8], pw[4];
#pragma unroll
    for (int p = 0; p < 8; ++p) {
      int f = p * 256 + tid;
      pa[p] = *reinterpret_cast<const uint4*>(Ab + (size_t)(f >> 3) * H_DIM + (f & 7) * 8);
    }
#pragma unroll
    for (int p = 0; p < 4; ++p) {
      int f = p * 256 + tid;
      pw[p] = *reinterpret_cast<const uint4*>(Wb + (size_t)(f >> 3) * H_DIM + (f & 7) * 8);
    }
    for (int k0 = 0; k0 < H_DIM; k0 += 64) {
#pragma unroll
      for (int p = 0; p < 8; ++p) {
        int f = p * 256 + tid;
        *reinterpret_cast<uint4*>(&sm.p1.A[f >> 3][(f & 7) * 8]) = pa[p];
      }
#pragma unroll
      for (int p = 0; p < 4; ++p) {
        int f = p * 256 + tid;
        *reinterpret_cast<uint4*>(&sm.p1.W[f >> 3][(f & 7) * 8]) = pw[p];
      }
      __syncthreads();
      if (k0 + 64 < H_DIM) {
#pragma unroll
        for (int p = 0; p < 8; ++p) {
          int f = p * 256 + tid;
          pa[p] = *reinterpret_cast<const uint4*>(Ab + (size_t)(f >> 3) * H_DIM + k0 + 64 + (f & 7) * 8);
        }
#pragma unroll
        for (int p = 0; p < 4; ++p) {
          int f = p * 256 + tid;
          pw[p] = *reinterpret_cast<const uint4*>(Wb + (size_t)(f >> 3) * H_DIM + k0 + 64 + (f & 7) * 8);
        }
      }
#pragma unroll
      for (int kk = 0; kk < 2; ++kk) {
        bf16x8 af[4];
#pragma unroll
        for (int mi = 0; mi < 4; ++mi)
          af[mi] = *reinterpret_cast<const bf16x8*>(&sm.p1.A[w * 64 + mi * 16 + lo][kk * 32 + hi * 8]);
#pragma unroll
        for (int ni = 0; ni < 8; ++ni) {
          bf16x8 bfr = *reinterpret_cast<const bf16x8*>(&sm.p1.W[ni * 16 + lo][kk * 32 + hi * 8]);
#pragma unroll
          for (int mi = 0; mi < 4; ++mi)
            acc[mi][ni] = __builtin_amdgcn_mfma_f32_16x16x32_bf16(af[mi], bfr, acc[mi][ni], 0, 0, 0);
        }
      }
      __syncthreads();
    }
  } else {
    const float* Ab = lhs + (size_t)b * (S_LEN * H_DIM);
    const int wc4 = tid & 31, wrg = tid >> 5;
    for (int k0 = 0; k0 < H_DIM; k0 += 64) {
#pragma unroll
      for (int p = 0; p < 16; ++p) {
        int f = p * 256 + tid;
        int m = f >> 4, c4 = f & 15;
        float4 v = *reinterpret_cast<const float4*>(Ab + (size_t)m * H_DIM + k0 + c4 * 4);
        *reinterpret_cast<ushort4*>(&sm.p1.A[m][c4 * 4]) =
            make_ushort4(f2bf(v.x), f2bf(v.y), f2bf(v.z), f2bf(v.w));
      }
      {
        ushort wt[8][4];
#pragma unroll
        for (int r8 = 0; r8 < 8; ++r8) {
          float4 v = *reinterpret_cast<const float4*>(
              Wd + (size_t)(k0 + wrg * 8 + r8) * WN + wcol0 + wc4 * 4);
          wt[r8][0] = f2bf(v.x); wt[r8][1] = f2bf(v.y);
          wt[r8][2] = f2bf(v.z); wt[r8][3] = f2bf(v.w);
        }
#pragma unroll
        for (int cc = 0; cc < 4; ++cc) {
          *reinterpret_cast<ushort4*>(&sm.p1.W[wc4 * 4 + cc][wrg * 8]) =
              make_ushort4(wt[0][cc], wt[1][cc], wt[2][cc], wt[3][cc]);
          *reinterpret_cast<ushort4*>(&sm.p1.W[wc4 * 4 + cc][wrg * 8 + 4]) =
              make_ushort4(wt[4][cc], wt[5][cc], wt[6][cc], wt[7][cc]);
        }
      }
      __syncthreads();
#pragma unroll
      for (int kk = 0; kk < 2; ++kk) {
        bf16x8 af[4];
#pragma unroll
        for (int mi = 0; mi < 4; ++mi)
          af[mi] = *reinterpret_cast<const bf16x8*>(&sm.p1.A[w * 64 + mi * 16 + lo][kk * 32 + hi * 8]);
#pragma unroll
        for (int ni = 0; ni < 8; ++ni) {
          bf16x8 bfr = *reinterpret_cast<const bf16x8*>(&sm.p1.W[ni * 16 + lo][kk * 32 + hi * 8]);
#pragma unroll
          for (int mi = 0; mi < 4; ++mi)
            acc[mi][ni] = __builtin_amdgcn_mfma_f32_16x16x32_bf16(af[mi], bfr, acc[mi][ni], 0, 0, 0);
        }
      }
      __syncthreads();
    }
  }

  // ---------------- bias + RoPE + write Q/K to LDS (overlaid) ----------------
  float bj[8];
#pragma unroll
  for (int ni = 0; ni < 8; ++ni) bj[ni] = bias[wcol0 + ni * 16 + lo];

  float inv_[4];
#pragma unroll
  for (int ii = 0; ii < 4; ++ii)
    inv_[ii] = exp2f(-(float)(ii * 8 + (lo >> 1)) * 0.4152410118609203f);  // log2(1e4)/32
  const float sgn = (lo & 1) ? 1.0f : -1.0f;

#pragma unroll
  for (int mi = 0; mi < 4; ++mi) {
#pragma unroll
    for (int r = 0; r < 4; ++r) {
      int m = w * 64 + mi * 16 + hi * 4 + r;  // 16x16 C/D row mapping (verified)
#pragma unroll
      for (int ii = 0; ii < 4; ++ii) {
        float sv, cv;
        __sincosf((float)m * inv_[ii], &sv, &cv);
        {
          float v = acc[mi][ii][r] + bj[ii];
          float o = __shfl_xor(v, 1);
          sm.p2.Q[m][ii * 16 + lo] = f2bf(v * cv + sgn * o * sv);
        }
        {
          float v = acc[mi][ii + 4][r] + bj[ii + 4];
          float o = __shfl_xor(v, 1);
          sm.p2.K[m][ii * 16 + lo] = f2bf(v * cv + sgn * o * sv);
        }
      }
    }
  }
  __syncthreads();

  // -------- phase 2: logits = Q @ K^T via 32x32x16 (full-cache-line stores) --------
  // A-frag: row = l31, k = hi2*8 + j per 16-k step; B-frag identical mapping
  // (consistent-k => HW permutation cancels). C/D: col=l31, row=(reg&3)+8*(reg>>2)+4*hi2.
  bf16x8 qf2[2][4];
#pragma unroll
  for (int mt = 0; mt < 2; ++mt)
#pragma unroll
    for (int ks = 0; ks < 4; ++ks)
      qf2[mt][ks] = *reinterpret_cast<const bf16x8*>(
          &sm.p2.Q[w * 64 + mt * 32 + l31][ks * 16 + hi2 * 8]);

  const size_t outbase = (size_t)bid * (S_LEN * (size_t)S_LEN);
  const int n = l31;  // column offset within ntile added below
#pragma unroll 1
  for (int nt = 0; nt < 8; ++nt) {
    bf16x8 kf2[4];
#pragma unroll
    for (int ks = 0; ks < 4; ++ks)
      kf2[ks] = *reinterpret_cast<const bf16x8*>(
          &sm.p2.K[nt * 32 + l31][ks * 16 + hi2 * 8]);

    const int ncol = nt * 32 + n;
    const float pad = mask_s[ncol];
    const float sub = (1.0f - pad) * NEGV;

#pragma unroll
    for (int mt = 0; mt < 2; ++mt) {
      f32x16 c2 = {};
#pragma unroll
      for (int ks = 0; ks < 4; ++ks)
        c2 = __builtin_amdgcn_mfma_f32_32x32x16_bf16(qf2[mt][ks], kf2[ks], c2, 0, 0, 0);

#pragma unroll
      for (int reg = 0; reg < 16; ++reg) {
        int m = w * 64 + mt * 32 + (reg & 3) + 8 * (reg >> 2) + 4 * hi2;
        float v = c2[reg] * pad - sub;
        if (m > ncol) v -= NEGV;  // tril(.., -1)
        __builtin_nontemporal_store(v * 0.125f, &out[outbase + (size_t)m * S_LEN + ncol]);
      }
    }
  }
}

extern "C" void kernel_launch(void* const* d_in, const int* in_sizes, int n_in,
                              void* d_out, int out_size, void* d_ws, size_t ws_size,
                              hipStream_t stream) {
  const float* lhs = (const float*)d_in[0];    // (64,256,768) f32
  const float* Wd = (const float*)d_in[1];     // (768,1664) f32
  const float* bias = (const float*)d_in[2];   // (1664,) f32
  const float* amask = (const float*)d_in[3];  // (64,256) f32
  float* out = (float*)d_out;                  // (64,13,256,256) f32

  const size_t lhsb_elems = (size_t)64 * S_LEN * H_DIM;
  const size_t wt_elems = (size_t)WN * H_DIM;
  const size_t need = (lhsb_elems + wt_elems) * sizeof(ushort);

  if (ws_size >= need) {
    ushort* lhsb = (ushort*)d_ws;
    ushort* wt = lhsb + lhsb_elems;
    prep_lhs<<<dim3((unsigned)(lhsb_elems / 8 / 256)), 256, 0, stream>>>(lhs, lhsb);
    prep_wt<<<dim3(12 * 26), 256, 0, stream>>>(Wd, wt);
    gp_kernel<true><<<dim3(64 * T_HEADS), 256, 0, stream>>>(lhs, Wd, bias, amask, lhsb, wt, out);
  } else {
    gp_kernel<false><<<dim3(64 * T_HEADS), 256, 0, stream>>>(lhs, Wd, bias, amask, nullptr, nullptr, out);
  }
}